// Round 10
// baseline (3976.468 us; speedup 1.0000x reference)
//
#include <hip/hip_runtime.h>
#include <hip/hip_fp16.h>

#define NNODES 20000
#define NEDGES 640000
#define NGRAPHS 16
#define NO     256
#define NNF    58
#define KPAD   64
#define EMBD   512
#define NL     28
#define NB     (NNODES / 4)   // edge-kernel node-blocks per pass

typedef __attribute__((ext_vector_type(8))) short bf16x8;
typedef __attribute__((ext_vector_type(4))) float f32x4;

__device__ __forceinline__ unsigned short f2bf(float f) {
    unsigned u = __float_as_uint(f);
    return (unsigned short)((u + 0x7fff + ((u >> 16) & 1)) >> 16);
}
__device__ __forceinline__ float bf2f(unsigned short h) {
    return __uint_as_float(((unsigned)h) << 16);
}

// ---------------- CSR build (once per launch) ----------------
__global__ __launch_bounds__(256) void k_hist(const int* __restrict__ dst, int* __restrict__ counts) {
    int e = blockIdx.x * 256 + threadIdx.x;
    if (e < NEDGES) atomicAdd(&counts[dst[e]], 1);
}

__global__ __launch_bounds__(256) void k_scan(const int* __restrict__ counts, int* __restrict__ offs) {
    __shared__ int part[256];
    int t = threadIdx.x;
    const int CH = (NNODES + 255) / 256;  // 79
    int base = t * CH;
    int s = 0;
    for (int i = 0; i < CH; ++i) { int idx = base + i; if (idx < NNODES) s += counts[idx]; }
    part[t] = s;
    __syncthreads();
    if (t == 0) { int acc = 0; for (int i = 0; i < 256; ++i) { int v = part[i]; part[i] = acc; acc += v; } }
    __syncthreads();
    int acc = part[t];
    for (int i = 0; i < CH; ++i) { int idx = base + i; if (idx < NNODES) { offs[idx] = acc; acc += counts[idx]; } }
    if (t == 255) offs[NNODES] = acc;
}

__global__ __launch_bounds__(256) void k_copy(const int* __restrict__ a, int* __restrict__ b, int n) {
    int i = blockIdx.x * 256 + threadIdx.x;
    if (i < n) b[i] = a[i];
}

// edge meta interleaved: em[pos] = (src, ef_bits) — one 8B load per edge in k_edge
__global__ __launch_bounds__(256) void k_fill(const int* __restrict__ src, const int* __restrict__ dst,
                                              const float* __restrict__ ef, int* __restrict__ cursor,
                                              int2* __restrict__ em) {
    int e = blockIdx.x * 256 + threadIdx.x;
    if (e < NEDGES) {
        int d = dst[e];
        int pos = atomicAdd(&cursor[d], 1);
        em[pos] = make_int2(src[e], __float_as_int(ef[e]));
    }
}

// ---------------- layer-0 input pad: [20000][58] -> [20000][64] fp32 ----------------
__global__ __launch_bounds__(256) void k_padx(const float* __restrict__ x, float* __restrict__ xpad) {
    int i = blockIdx.x * 256 + threadIdx.x;
    if (i < NNODES * KPAD) {
        int r = i >> 6, c = i & 63;
        xpad[i] = (c < NNF) ? x[r * NNF + c] : 0.f;
    }
}

// ---------------- weight precompute (bf16 hi/lo split) ----------------
// W rows: 0..255 = Wn; 256..511 = SCL*(Wm*diag(We))@Wn; 512..767 = SCL*(Wm*diag(be))@Wn
#define SCL 2.8853900817779268f

__global__ __launch_bounds__(256) void k_prepA(
    const float* __restrict__ Wn0, const float* __restrict__ bn0,
    const float* __restrict__ Wn,  const float* __restrict__ bn,
    unsigned short* __restrict__ Whi, unsigned short* __restrict__ Wlo,
    float* __restrict__ bcat) {
    int gid = blockIdx.x * 256 + threadIdx.x;
    if (gid >= NL * NO * NO) return;
    int l = gid / (NO * NO);
    int rem = gid % (NO * NO);
    int r = rem / NO, k = rem % NO;
    float w;
    if (l == 0) w = (k < NNF) ? Wn0[r * NNF + k] : 0.f;
    else        w = Wn[(size_t)(l - 1) * NO * NO + r * NO + k];
    unsigned short hi = f2bf(w);
    unsigned short lo = f2bf(w - bf2f(hi));
    size_t idx = ((size_t)l * 768 + r) * NO + k;
    Whi[idx] = hi; Wlo[idx] = lo;
    if (k == 0) bcat[l * 768 + r] = (l == 0) ? bn0[r] : bn[(l - 1) * NO + r];
}

// 16 rows/block
__global__ __launch_bounds__(256) void k_prepB(
    const float* __restrict__ Wn0, const float* __restrict__ bn0,
    const float* __restrict__ We0, const float* __restrict__ be0,
    const float* __restrict__ Wm0, const float* __restrict__ bm0,
    const float* __restrict__ Wn,  const float* __restrict__ bn,
    const float* __restrict__ We,  const float* __restrict__ be,
    const float* __restrict__ Wm,  const float* __restrict__ bm,
    unsigned short* __restrict__ Whi, unsigned short* __restrict__ Wlo,
    float* __restrict__ bcat) {
    int l = blockIdx.x >> 5;
    int rr0 = (blockIdx.x & 31) * 16;
    int k = threadIdx.x;
    const float *wn, *bnv, *wev, *bev, *wm, *bmv;
    int K;
    if (l == 0) { wn = Wn0; bnv = bn0; wev = We0; bev = be0; wm = Wm0; bmv = bm0; K = NNF; }
    else {
        int j = l - 1;
        wn = Wn + (size_t)j * NO * NO; bnv = bn + j * NO;
        wev = We + j * NO;             bev = be + j * NO;
        wm = Wm + (size_t)j * NO * NO; bmv = bm + j * NO;
        K = NO;
    }
    __shared__ float coeff[16][NO + 1];
    for (int q = 0; q < 16; ++q) {
        int rr = rr0 + q;
        int i = rr & 255;
        const float* scale = (rr < 256) ? wev : bev;
        coeff[q][k] = wm[(size_t)i * NO + k] * scale[k];
    }
    __syncthreads();
    float acc[16] = {};
    if (k < K) {
        for (int j = 0; j < NO; ++j) {
            float wv = wn[(size_t)j * K + k];
            #pragma unroll
            for (int q = 0; q < 16; ++q) acc[q] += coeff[q][j] * wv;
        }
    }
    for (int q = 0; q < 16; ++q) {
        float w = (k < K) ? acc[q] * SCL : 0.f;
        unsigned short hi = f2bf(w);
        unsigned short lo = f2bf(w - bf2f(hi));
        size_t idx = ((size_t)l * 768 + 256 + rr0 + q) * NO + k;
        Whi[idx] = hi; Wlo[idx] = lo;
    }
    if (k < 16) {
        int rr = rr0 + k;
        int i = rr & 255;
        float b = 0.f;
        for (int j = 0; j < NO; ++j) b += coeff[k][j] * bnv[j];
        if (rr >= 256) b += bmv[i];
        bcat[l * 768 + 256 + rr] = b * SCL;
    }
}

// ---------------- MFMA layer GEMM (LDS-staged, on-the-fly A split) ----------------
#define LDP 40
__global__ __launch_bounds__(256) void k_gemm(const float* __restrict__ A,
                                              const unsigned short* __restrict__ Whi,
                                              const unsigned short* __restrict__ Wlo,
                                              const float* __restrict__ bias,
                                              float* __restrict__ HN, __half* __restrict__ UV,
                                              int M, int K) {
    __shared__ short sAhi[128 * LDP];
    __shared__ short sAlo[128 * LDP];
    __shared__ short sBhi[128 * LDP];
    __shared__ short sBlo[128 * LDP];
    int bn0 = blockIdx.x * 128;
    int bm0 = blockIdx.y * 128;
    int t = threadIdx.x;
    int wid = t >> 6, lane = t & 63;
    int wr = wid >> 1, wc = wid & 1;
    int lr = lane & 15, lg = lane >> 4;
    int kofs = lg * 8;
    f32x4 acc[4][4] = {};

    int srow = t >> 1, skh = (t & 1) * 16;

    for (int k0 = 0; k0 < K; k0 += 32) {
        {
            int gr = bm0 + srow;
            float f[16];
            if (gr < M) {
                #pragma unroll
                for (int q = 0; q < 4; ++q)
                    *(float4*)(f + 4 * q) = *(const float4*)(A + (size_t)gr * K + k0 + skh + 4 * q);
            } else {
                #pragma unroll
                for (int q = 0; q < 16; ++q) f[q] = 0.f;
            }
            int ph[8], pl[8];
            #pragma unroll
            for (int q = 0; q < 8; ++q) {
                unsigned short h0 = f2bf(f[2 * q]);
                unsigned short h1 = f2bf(f[2 * q + 1]);
                unsigned short l0 = f2bf(f[2 * q] - bf2f(h0));
                unsigned short l1 = f2bf(f[2 * q + 1] - bf2f(h1));
                ph[q] = (int)h0 | ((int)h1 << 16);
                pl[q] = (int)l0 | ((int)l1 << 16);
            }
            *(int4*)(void*)(sAhi + srow * LDP + skh)     = *(int4*)(void*)(ph);
            *(int4*)(void*)(sAhi + srow * LDP + skh + 8) = *(int4*)(void*)(ph + 4);
            *(int4*)(void*)(sAlo + srow * LDP + skh)     = *(int4*)(void*)(pl);
            *(int4*)(void*)(sAlo + srow * LDP + skh + 8) = *(int4*)(void*)(pl + 4);
        }
        {
            const unsigned short* gh = Whi + (size_t)(bn0 + srow) * NO + k0 + skh;
            const unsigned short* gl = Wlo + (size_t)(bn0 + srow) * NO + k0 + skh;
            *(int4*)(void*)(sBhi + srow * LDP + skh)     = *(const int4*)(void*)(gh);
            *(int4*)(void*)(sBhi + srow * LDP + skh + 8) = *(const int4*)(void*)(gh + 8);
            *(int4*)(void*)(sBlo + srow * LDP + skh)     = *(const int4*)(void*)(gl);
            *(int4*)(void*)(sBlo + srow * LDP + skh + 8) = *(const int4*)(void*)(gl + 8);
        }
        __syncthreads();
        bf16x8 ah[4], al[4], wh[4], wl[4];
        #pragma unroll
        for (int f = 0; f < 4; ++f) {
            ah[f] = *(bf16x8*)(void*)(sAhi + (wr * 64 + f * 16 + lr) * LDP + kofs);
            al[f] = *(bf16x8*)(void*)(sAlo + (wr * 64 + f * 16 + lr) * LDP + kofs);
            wh[f] = *(bf16x8*)(void*)(sBhi + (wc * 64 + f * 16 + lr) * LDP + kofs);
            wl[f] = *(bf16x8*)(void*)(sBlo + (wc * 64 + f * 16 + lr) * LDP + kofs);
        }
        #pragma unroll
        for (int fc = 0; fc < 4; ++fc)
            #pragma unroll
            for (int fr = 0; fr < 4; ++fr) {
                acc[fc][fr] = __builtin_amdgcn_mfma_f32_16x16x32_bf16(wh[fc], ah[fr], acc[fc][fr], 0, 0, 0);
                acc[fc][fr] = __builtin_amdgcn_mfma_f32_16x16x32_bf16(wh[fc], al[fr], acc[fc][fr], 0, 0, 0);
                acc[fc][fr] = __builtin_amdgcn_mfma_f32_16x16x32_bf16(wl[fc], ah[fr], acc[fc][fr], 0, 0, 0);
            }
        __syncthreads();
    }
    #pragma unroll
    for (int fc = 0; fc < 4; ++fc) {
        int n0 = bn0 + wc * 64 + fc * 16 + lg * 4;
        float4 bi = *(const float4*)(bias + n0);
        #pragma unroll
        for (int fr = 0; fr < 4; ++fr) {
            int gr = bm0 + wr * 64 + fr * 16 + lr;
            if (gr >= M) continue;
            f32x4 v = acc[fc][fr];
            float o0 = v[0] + bi.x, o1 = v[1] + bi.y, o2 = v[2] + bi.z, o3 = v[3] + bi.w;
            if (n0 < 256) {
                float4 o = {o0, o1, o2, o3};
                *(float4*)(HN + (size_t)gr * NO + n0) = o;
            } else {
                int i0 = (n0 < 512) ? n0 - 256 : n0 - 512;
                int base = 2 * i0 + ((n0 < 512) ? 0 : 4);
                union { __half2 h2[2]; uint2 u; } pk;
                pk.h2[0] = __floats2half2_rn(o0, o1);
                pk.h2[1] = __floats2half2_rn(o2, o3);
                *(uint2*)(UV + (size_t)gr * 512 + base) = pk.u;
            }
        }
    }
}

// ---------------- edge aggregation: channel-chunked, per-lane edge meta, fp16-z ----------------
// pass c touches UV[:, 128c..128c+127]; wave = 4 edge-slots (es) x 16 channel-lanes (cl).
// Sum(tanh) = cnt - 2*Sum(rcp(exp2(z)+1)); unroll-by-2 pairs the em->UV dependent loads.
__global__ __launch_bounds__(256) void k_edge(const float* __restrict__ HN, const __half* __restrict__ UV,
                                              const int* __restrict__ offs,
                                              const int2* __restrict__ em,
                                              float* __restrict__ hout) {
    int blk = blockIdx.x;
    int pass = blk / NB;          // 0..3, linear dispatch keeps passes roughly sequential
    int nb   = blk - pass * NB;
    int wv = threadIdx.x >> 6;
    int lane = threadIdx.x & 63;
    int n = nb * 4 + wv;
    int es = lane >> 4, cl = lane & 15;
    int e0 = offs[n], e1 = offs[n + 1];
    float r0 = 0.f, r1 = 0.f, r2 = 0.f, r3 = 0.f;
    const __half* uvb = UV + pass * 128 + cl * 8;
    for (int e = e0 + es; e < e1; e += 8) {
        int e2 = e + 4;
        bool v1 = e2 < e1;
        int e2c = v1 ? e2 : e;
        int2 m0 = em[e];            // both meta loads issue together
        int2 m1 = em[e2c];
        float4 raw0 = *(const float4*)(uvb + (size_t)m0.x * 512);   // both gathers issue together
        float4 raw1 = *(const float4*)(uvb + (size_t)m1.x * 512);
        __half2 f0 = __half2half2(__float2half_rn(__int_as_float(m0.y)));
        const __half2* h0 = (const __half2*)&raw0;
        __half2 za = __hfma2(f0, h0[0], h0[2]);
        __half2 zb = __hfma2(f0, h0[1], h0[3]);
        float2 xa = __half22float2(za);
        float2 xb = __half22float2(zb);
        r0 += __builtin_amdgcn_rcpf(exp2f(xa.x) + 1.0f);
        r1 += __builtin_amdgcn_rcpf(exp2f(xa.y) + 1.0f);
        r2 += __builtin_amdgcn_rcpf(exp2f(xb.x) + 1.0f);
        r3 += __builtin_amdgcn_rcpf(exp2f(xb.y) + 1.0f);
        if (v1) {
            __half2 f1 = __half2half2(__float2half_rn(__int_as_float(m1.y)));
            const __half2* h1 = (const __half2*)&raw1;
            __half2 zc = __hfma2(f1, h1[0], h1[2]);
            __half2 zd = __hfma2(f1, h1[1], h1[3]);
            float2 xc = __half22float2(zc);
            float2 xd = __half22float2(zd);
            r0 += __builtin_amdgcn_rcpf(exp2f(xc.x) + 1.0f);
            r1 += __builtin_amdgcn_rcpf(exp2f(xc.y) + 1.0f);
            r2 += __builtin_amdgcn_rcpf(exp2f(xd.x) + 1.0f);
            r3 += __builtin_amdgcn_rcpf(exp2f(xd.y) + 1.0f);
        }
    }
    r0 += __shfl_xor(r0, 16); r0 += __shfl_xor(r0, 32);
    r1 += __shfl_xor(r1, 16); r1 += __shfl_xor(r1, 32);
    r2 += __shfl_xor(r2, 16); r2 += __shfl_xor(r2, 32);
    r3 += __shfl_xor(r3, 16); r3 += __shfl_xor(r3, 32);
    if (es == 0) {
        float cnt = (float)(e1 - e0);
        int c0 = pass * 64 + cl * 4;
        float4 hn4 = *(const float4*)(HN + (size_t)n * NO + c0);
        float4 o = {hn4.x + cnt - 2.f * r0, hn4.y + cnt - 2.f * r1,
                    hn4.z + cnt - 2.f * r2, hn4.w + cnt - 2.f * r3};
        *(float4*)(hout + (size_t)n * NO + c0) = o;
    }
}

// ---------------- pooling via sorted-batch ranges ----------------
__device__ __forceinline__ int lower_bound_g(const int* __restrict__ batch, int target) {
    int lo = 0, hi = NNODES;
    while (lo < hi) { int mid = (lo + hi) >> 1; if (batch[mid] < target) lo = mid + 1; else hi = mid; }
    return lo;
}

__global__ __launch_bounds__(256) void k_pool2(const float* __restrict__ h, const int* __restrict__ batch,
                                               float* __restrict__ sums) {
    int g = blockIdx.x, chunk = blockIdx.y;
    __shared__ int sh[2];
    if (threadIdx.x < 2) sh[threadIdx.x] = lower_bound_g(batch, g + (int)threadIdx.x);
    __syncthreads();
    int lo = sh[0], hi = sh[1];
    float acc = 0.f;
    for (int r = lo + chunk; r < hi; r += 8)
        acc += h[(size_t)r * NO + threadIdx.x];
    atomicAdd(&sums[g * NO + threadIdx.x], acc);
}

__global__ __launch_bounds__(512) void k_final(const float* __restrict__ sums, const int* __restrict__ batch,
                                               const float* __restrict__ Wlin, const float* __restrict__ blin,
                                               float* __restrict__ out) {
    int g = blockIdx.x, t = threadIdx.x;
    __shared__ int sh[2];
    __shared__ float m[NO];
    if (t < 2) sh[t] = lower_bound_g(batch, g + t);
    __syncthreads();
    float inv = 1.f / (float)(sh[1] - sh[0]);
    if (t < NO) m[t] = sums[g * NO + t] * inv;
    __syncthreads();
    float acc = blin[t];
    for (int k = 0; k < NO; ++k) acc += m[k] * Wlin[(size_t)t * NO + k];
    out[(size_t)g * EMBD + t] = acc;
}

extern "C" void kernel_launch(void* const* d_in, const int* in_sizes, int n_in,
                              void* d_out, int out_size, void* d_ws, size_t ws_size,
                              hipStream_t stream) {
    const float* x     = (const float*)d_in[0];
    const int*   ei    = (const int*)d_in[1];
    const float* ef    = (const float*)d_in[2];
    const int*   batch = (const int*)d_in[3];
    const float* Wn0 = (const float*)d_in[4];
    const float* bn0 = (const float*)d_in[5];
    const float* We0 = (const float*)d_in[6];
    const float* be0 = (const float*)d_in[7];
    const float* Wm0 = (const float*)d_in[8];
    const float* bm0 = (const float*)d_in[9];
    const float* Wn  = (const float*)d_in[10];
    const float* bn  = (const float*)d_in[11];
    const float* We  = (const float*)d_in[12];
    const float* be  = (const float*)d_in[13];
    const float* Wm  = (const float*)d_in[14];
    const float* bm  = (const float*)d_in[15];
    const float* Wlin = (const float*)d_in[16];
    const float* blin = (const float*)d_in[17];
    float* out = (float*)d_out;

    // workspace carve (256B aligned slices)
    char* p = (char*)d_ws;
    auto carve = [&](size_t bytes) { char* q = p; p += (bytes + 255) & ~(size_t)255; return q; };
    float*  h    = (float*)carve((size_t)NNODES * NO * 4);            // 20.48 MB
    float*  HN   = (float*)carve((size_t)NNODES * NO * 4);            // 20.48 MB
    __half* UV   = (__half*)carve((size_t)NNODES * 512 * 2);          // 20.48 MB
    unsigned short* Whi = (unsigned short*)carve((size_t)NL * 768 * NO * 2);  // 11.0 MB
    unsigned short* Wlo = (unsigned short*)carve((size_t)NL * 768 * NO * 2);  // 11.0 MB
    float*  bcat = (float*)carve((size_t)NL * 768 * 4);
    float*  xpad = (float*)carve((size_t)NNODES * KPAD * 4);          // 5.12 MB
    int*    offs = (int*)carve((size_t)(NNODES + 1) * 4);
    int*    cur  = (int*)carve((size_t)NNODES * 4);
    int2*   em   = (int2*)carve((size_t)NEDGES * 8);                  // 5.12 MB
    float*  sums = (float*)carve((size_t)NGRAPHS * NO * 4);

    const int* src = ei;
    const int* dst = ei + NEDGES;

    // CSR build
    hipMemsetAsync(cur, 0, (size_t)NNODES * 4, stream);
    k_hist<<<NEDGES / 256, 256, 0, stream>>>(dst, cur);
    k_scan<<<1, 256, 0, stream>>>(cur, offs);
    k_copy<<<(NNODES + 255) / 256, 256, 0, stream>>>(offs, cur, NNODES);
    k_fill<<<NEDGES / 256, 256, 0, stream>>>(src, dst, ef, cur, em);

    // layer-0 padded input + composed per-layer weights (bf16 hi/lo)
    k_padx<<<(NNODES * KPAD + 255) / 256, 256, 0, stream>>>(x, xpad);
    k_prepA<<<(NL * NO * NO + 255) / 256, 256, 0, stream>>>(Wn0, bn0, Wn, bn, Whi, Wlo, bcat);
    k_prepB<<<NL * 32, 256, 0, stream>>>(Wn0, bn0, We0, be0, Wm0, bm0,
                                         Wn, bn, We, be, Wm, bm, Whi, Wlo, bcat);

    // 28 layers
    for (int l = 0; l < NL; ++l) {
        const float* Ain = (l == 0) ? xpad : h;
        int K = (l == 0) ? KPAD : NO;
        dim3 grid(768 / 128, (NNODES + 127) / 128);
        k_gemm<<<grid, 256, 0, stream>>>(Ain, Whi + (size_t)l * 768 * NO, Wlo + (size_t)l * 768 * NO,
                                         bcat + (size_t)l * 768, HN, UV, NNODES, K);
        k_edge<<<4 * NB, 256, 0, stream>>>(HN, UV, offs, em, h);
    }

    // mean-pool via sorted ranges, then tiny final GEMM
    hipMemsetAsync(sums, 0, (size_t)NGRAPHS * NO * 4, stream);
    dim3 pg(NGRAPHS, 8);
    k_pool2<<<pg, 256, 0, stream>>>(h, batch, sums);
    k_final<<<NGRAPHS, 512, 0, stream>>>(sums, batch, Wlin, blin, out);
}

// Round 11
// 3540.570 us; speedup vs baseline: 1.1231x; 1.1231x over previous
//
#include <hip/hip_runtime.h>
#include <hip/hip_fp16.h>

#define NNODES 20000
#define NEDGES 640000
#define NGRAPHS 16
#define NO     256
#define NNF    58
#define KPAD   64
#define EMBD   512
#define NL     28
#define NB     (NNODES / 4)   // edge-kernel node-blocks per pass

typedef __attribute__((ext_vector_type(8))) short bf16x8;
typedef __attribute__((ext_vector_type(4))) float f32x4;

__device__ __forceinline__ unsigned short f2bf(float f) {
    unsigned u = __float_as_uint(f);
    return (unsigned short)((u + 0x7fff + ((u >> 16) & 1)) >> 16);
}
__device__ __forceinline__ float bf2f(unsigned short h) {
    return __uint_as_float(((unsigned)h) << 16);
}

// ---------------- CSR build (once per launch) ----------------
__global__ __launch_bounds__(256) void k_hist(const int* __restrict__ dst, int* __restrict__ counts) {
    int e = blockIdx.x * 256 + threadIdx.x;
    if (e < NEDGES) atomicAdd(&counts[dst[e]], 1);
}

__global__ __launch_bounds__(256) void k_scan(const int* __restrict__ counts, int* __restrict__ offs) {
    __shared__ int part[256];
    int t = threadIdx.x;
    const int CH = (NNODES + 255) / 256;  // 79
    int base = t * CH;
    int s = 0;
    for (int i = 0; i < CH; ++i) { int idx = base + i; if (idx < NNODES) s += counts[idx]; }
    part[t] = s;
    __syncthreads();
    if (t == 0) { int acc = 0; for (int i = 0; i < 256; ++i) { int v = part[i]; part[i] = acc; acc += v; } }
    __syncthreads();
    int acc = part[t];
    for (int i = 0; i < CH; ++i) { int idx = base + i; if (idx < NNODES) { offs[idx] = acc; acc += counts[idx]; } }
    if (t == 255) offs[NNODES] = acc;
}

__global__ __launch_bounds__(256) void k_copy(const int* __restrict__ a, int* __restrict__ b, int n) {
    int i = blockIdx.x * 256 + threadIdx.x;
    if (i < n) b[i] = a[i];
}

// edge meta interleaved: em[pos] = (src, ef as packed half2) — ef pre-converted once
__global__ __launch_bounds__(256) void k_fill(const int* __restrict__ src, const int* __restrict__ dst,
                                              const float* __restrict__ ef, int* __restrict__ cursor,
                                              int2* __restrict__ em) {
    int e = blockIdx.x * 256 + threadIdx.x;
    if (e < NEDGES) {
        int d = dst[e];
        int pos = atomicAdd(&cursor[d], 1);
        float f = ef[e];
        __half2 hf = __floats2half2_rn(f, f);
        em[pos] = make_int2(src[e], *(int*)&hf);
    }
}

// ---------------- layer-0 input pad: [20000][58] -> [20000][64] fp32 ----------------
__global__ __launch_bounds__(256) void k_padx(const float* __restrict__ x, float* __restrict__ xpad) {
    int i = blockIdx.x * 256 + threadIdx.x;
    if (i < NNODES * KPAD) {
        int r = i >> 6, c = i & 63;
        xpad[i] = (c < NNF) ? x[r * NNF + c] : 0.f;
    }
}

// ---------------- weight precompute (bf16 hi/lo split) ----------------
// W rows: 0..255 = Wn; 256..511 = SCL*(Wm*diag(We))@Wn; 512..767 = SCL*(Wm*diag(be))@Wn
#define SCL 2.8853900817779268f

__global__ __launch_bounds__(256) void k_prepA(
    const float* __restrict__ Wn0, const float* __restrict__ bn0,
    const float* __restrict__ Wn,  const float* __restrict__ bn,
    unsigned short* __restrict__ Whi, unsigned short* __restrict__ Wlo,
    float* __restrict__ bcat) {
    int gid = blockIdx.x * 256 + threadIdx.x;
    if (gid >= NL * NO * NO) return;
    int l = gid / (NO * NO);
    int rem = gid % (NO * NO);
    int r = rem / NO, k = rem % NO;
    float w;
    if (l == 0) w = (k < NNF) ? Wn0[r * NNF + k] : 0.f;
    else        w = Wn[(size_t)(l - 1) * NO * NO + r * NO + k];
    unsigned short hi = f2bf(w);
    unsigned short lo = f2bf(w - bf2f(hi));
    size_t idx = ((size_t)l * 768 + r) * NO + k;
    Whi[idx] = hi; Wlo[idx] = lo;
    if (k == 0) bcat[l * 768 + r] = (l == 0) ? bn0[r] : bn[(l - 1) * NO + r];
}

// 16 rows/block
__global__ __launch_bounds__(256) void k_prepB(
    const float* __restrict__ Wn0, const float* __restrict__ bn0,
    const float* __restrict__ We0, const float* __restrict__ be0,
    const float* __restrict__ Wm0, const float* __restrict__ bm0,
    const float* __restrict__ Wn,  const float* __restrict__ bn,
    const float* __restrict__ We,  const float* __restrict__ be,
    const float* __restrict__ Wm,  const float* __restrict__ bm,
    unsigned short* __restrict__ Whi, unsigned short* __restrict__ Wlo,
    float* __restrict__ bcat) {
    int l = blockIdx.x >> 5;
    int rr0 = (blockIdx.x & 31) * 16;
    int k = threadIdx.x;
    const float *wn, *bnv, *wev, *bev, *wm, *bmv;
    int K;
    if (l == 0) { wn = Wn0; bnv = bn0; wev = We0; bev = be0; wm = Wm0; bmv = bm0; K = NNF; }
    else {
        int j = l - 1;
        wn = Wn + (size_t)j * NO * NO; bnv = bn + j * NO;
        wev = We + j * NO;             bev = be + j * NO;
        wm = Wm + (size_t)j * NO * NO; bmv = bm + j * NO;
        K = NO;
    }
    __shared__ float coeff[16][NO + 1];
    for (int q = 0; q < 16; ++q) {
        int rr = rr0 + q;
        int i = rr & 255;
        const float* scale = (rr < 256) ? wev : bev;
        coeff[q][k] = wm[(size_t)i * NO + k] * scale[k];
    }
    __syncthreads();
    float acc[16] = {};
    if (k < K) {
        for (int j = 0; j < NO; ++j) {
            float wv = wn[(size_t)j * K + k];
            #pragma unroll
            for (int q = 0; q < 16; ++q) acc[q] += coeff[q][j] * wv;
        }
    }
    for (int q = 0; q < 16; ++q) {
        float w = (k < K) ? acc[q] * SCL : 0.f;
        unsigned short hi = f2bf(w);
        unsigned short lo = f2bf(w - bf2f(hi));
        size_t idx = ((size_t)l * 768 + 256 + rr0 + q) * NO + k;
        Whi[idx] = hi; Wlo[idx] = lo;
    }
    if (k < 16) {
        int rr = rr0 + k;
        int i = rr & 255;
        float b = 0.f;
        for (int j = 0; j < NO; ++j) b += coeff[k][j] * bnv[j];
        if (rr >= 256) b += bmv[i];
        bcat[l * 768 + 256 + rr] = b * SCL;
    }
}

// ---------------- MFMA layer GEMM (LDS-staged, on-the-fly A split) ----------------
#define LDP 40
__global__ __launch_bounds__(256) void k_gemm(const float* __restrict__ A,
                                              const unsigned short* __restrict__ Whi,
                                              const unsigned short* __restrict__ Wlo,
                                              const float* __restrict__ bias,
                                              float* __restrict__ HN, __half* __restrict__ UV,
                                              int M, int K) {
    __shared__ short sAhi[128 * LDP];
    __shared__ short sAlo[128 * LDP];
    __shared__ short sBhi[128 * LDP];
    __shared__ short sBlo[128 * LDP];
    int bn0 = blockIdx.x * 128;
    int bm0 = blockIdx.y * 128;
    int t = threadIdx.x;
    int wid = t >> 6, lane = t & 63;
    int wr = wid >> 1, wc = wid & 1;
    int lr = lane & 15, lg = lane >> 4;
    int kofs = lg * 8;
    f32x4 acc[4][4] = {};

    int srow = t >> 1, skh = (t & 1) * 16;

    for (int k0 = 0; k0 < K; k0 += 32) {
        {
            int gr = bm0 + srow;
            float f[16];
            if (gr < M) {
                #pragma unroll
                for (int q = 0; q < 4; ++q)
                    *(float4*)(f + 4 * q) = *(const float4*)(A + (size_t)gr * K + k0 + skh + 4 * q);
            } else {
                #pragma unroll
                for (int q = 0; q < 16; ++q) f[q] = 0.f;
            }
            int ph[8], pl[8];
            #pragma unroll
            for (int q = 0; q < 8; ++q) {
                unsigned short h0 = f2bf(f[2 * q]);
                unsigned short h1 = f2bf(f[2 * q + 1]);
                unsigned short l0 = f2bf(f[2 * q] - bf2f(h0));
                unsigned short l1 = f2bf(f[2 * q + 1] - bf2f(h1));
                ph[q] = (int)h0 | ((int)h1 << 16);
                pl[q] = (int)l0 | ((int)l1 << 16);
            }
            *(int4*)(void*)(sAhi + srow * LDP + skh)     = *(int4*)(void*)(ph);
            *(int4*)(void*)(sAhi + srow * LDP + skh + 8) = *(int4*)(void*)(ph + 4);
            *(int4*)(void*)(sAlo + srow * LDP + skh)     = *(int4*)(void*)(pl);
            *(int4*)(void*)(sAlo + srow * LDP + skh + 8) = *(int4*)(void*)(pl + 4);
        }
        {
            const unsigned short* gh = Whi + (size_t)(bn0 + srow) * NO + k0 + skh;
            const unsigned short* gl = Wlo + (size_t)(bn0 + srow) * NO + k0 + skh;
            *(int4*)(void*)(sBhi + srow * LDP + skh)     = *(const int4*)(void*)(gh);
            *(int4*)(void*)(sBhi + srow * LDP + skh + 8) = *(const int4*)(void*)(gh + 8);
            *(int4*)(void*)(sBlo + srow * LDP + skh)     = *(const int4*)(void*)(gl);
            *(int4*)(void*)(sBlo + srow * LDP + skh + 8) = *(const int4*)(void*)(gl + 8);
        }
        __syncthreads();
        bf16x8 ah[4], al[4], wh[4], wl[4];
        #pragma unroll
        for (int f = 0; f < 4; ++f) {
            ah[f] = *(bf16x8*)(void*)(sAhi + (wr * 64 + f * 16 + lr) * LDP + kofs);
            al[f] = *(bf16x8*)(void*)(sAlo + (wr * 64 + f * 16 + lr) * LDP + kofs);
            wh[f] = *(bf16x8*)(void*)(sBhi + (wc * 64 + f * 16 + lr) * LDP + kofs);
            wl[f] = *(bf16x8*)(void*)(sBlo + (wc * 64 + f * 16 + lr) * LDP + kofs);
        }
        #pragma unroll
        for (int fc = 0; fc < 4; ++fc)
            #pragma unroll
            for (int fr = 0; fr < 4; ++fr) {
                acc[fc][fr] = __builtin_amdgcn_mfma_f32_16x16x32_bf16(wh[fc], ah[fr], acc[fc][fr], 0, 0, 0);
                acc[fc][fr] = __builtin_amdgcn_mfma_f32_16x16x32_bf16(wh[fc], al[fr], acc[fc][fr], 0, 0, 0);
                acc[fc][fr] = __builtin_amdgcn_mfma_f32_16x16x32_bf16(wl[fc], ah[fr], acc[fc][fr], 0, 0, 0);
            }
        __syncthreads();
    }
    #pragma unroll
    for (int fc = 0; fc < 4; ++fc) {
        int n0 = bn0 + wc * 64 + fc * 16 + lg * 4;
        float4 bi = *(const float4*)(bias + n0);
        #pragma unroll
        for (int fr = 0; fr < 4; ++fr) {
            int gr = bm0 + wr * 64 + fr * 16 + lr;
            if (gr >= M) continue;
            f32x4 v = acc[fc][fr];
            float o0 = v[0] + bi.x, o1 = v[1] + bi.y, o2 = v[2] + bi.z, o3 = v[3] + bi.w;
            if (n0 < 256) {
                float4 o = {o0, o1, o2, o3};
                *(float4*)(HN + (size_t)gr * NO + n0) = o;
            } else {
                int i0 = (n0 < 512) ? n0 - 256 : n0 - 512;
                int base = 2 * i0 + ((n0 < 512) ? 0 : 4);
                union { __half2 h2[2]; uint2 u; } pk;
                pk.h2[0] = __floats2half2_rn(o0, o1);
                pk.h2[1] = __floats2half2_rn(o2, o3);
                *(uint2*)(UV + (size_t)gr * 512 + base) = pk.u;
            }
        }
    }
}

// ---------------- edge aggregation: channel-chunked + shfl-broadcast meta + fp16-z ----------------
// pass c touches UV[:, 128c..128c+127]; wave = 4 edge-slots (es) x 16 channel-lanes (cl).
// 64 metas preloaded coalesced per batch (int2: src + prepacked half2 ef);
// shfl-broadcast keeps gather indices register-resident -> gathers pipeline back-to-back.
// Sum(tanh) = cnt - 2*Sum(rcp(exp2(z)+1)).
__global__ __launch_bounds__(256) void k_edge(const float* __restrict__ HN, const __half* __restrict__ UV,
                                              const int* __restrict__ offs,
                                              const int2* __restrict__ em,
                                              float* __restrict__ hout) {
    int blk = blockIdx.x;
    int pass = blk / NB;          // 0..3, linear dispatch keeps passes roughly sequential
    int nb   = blk - pass * NB;
    int wv = threadIdx.x >> 6;
    int lane = threadIdx.x & 63;
    int n = nb * 4 + wv;
    int es = lane >> 4, cl = lane & 15;
    int e0 = offs[n], e1 = offs[n + 1];
    float r0 = 0.f, r1 = 0.f, r2 = 0.f, r3 = 0.f;
    const __half* uvb = UV + pass * 128 + cl * 8;
    for (int eb = e0; eb < e1; eb += 64) {
        int cnt = e1 - eb; if (cnt > 64) cnt = 64;
        int2 mv = make_int2(0, 0);
        if (lane < cnt) mv = em[eb + lane];
        #pragma unroll 4
        for (int i = 0; i < cnt; i += 4) {
            int j = i + es;
            int ss = __shfl(mv.x, j);
            int fb = __shfl(mv.y, j);
            if (j < cnt) {
                float4 raw = *(const float4*)(uvb + (size_t)ss * 512);
                const __half2* hp = (const __half2*)&raw;
                __half2 f = *(__half2*)&fb;
                __half2 za = __hfma2(f, hp[0], hp[2]);
                __half2 zb = __hfma2(f, hp[1], hp[3]);
                float2 xa = __half22float2(za);
                float2 xb = __half22float2(zb);
                r0 += __builtin_amdgcn_rcpf(exp2f(xa.x) + 1.0f);
                r1 += __builtin_amdgcn_rcpf(exp2f(xa.y) + 1.0f);
                r2 += __builtin_amdgcn_rcpf(exp2f(xb.x) + 1.0f);
                r3 += __builtin_amdgcn_rcpf(exp2f(xb.y) + 1.0f);
            }
        }
    }
    r0 += __shfl_xor(r0, 16); r0 += __shfl_xor(r0, 32);
    r1 += __shfl_xor(r1, 16); r1 += __shfl_xor(r1, 32);
    r2 += __shfl_xor(r2, 16); r2 += __shfl_xor(r2, 32);
    r3 += __shfl_xor(r3, 16); r3 += __shfl_xor(r3, 32);
    if (es == 0) {
        float cnt = (float)(e1 - e0);
        int c0 = pass * 64 + cl * 4;
        float4 hn4 = *(const float4*)(HN + (size_t)n * NO + c0);
        float4 o = {hn4.x + cnt - 2.f * r0, hn4.y + cnt - 2.f * r1,
                    hn4.z + cnt - 2.f * r2, hn4.w + cnt - 2.f * r3};
        *(float4*)(hout + (size_t)n * NO + c0) = o;
    }
}

// ---------------- pooling via sorted-batch ranges ----------------
__device__ __forceinline__ int lower_bound_g(const int* __restrict__ batch, int target) {
    int lo = 0, hi = NNODES;
    while (lo < hi) { int mid = (lo + hi) >> 1; if (batch[mid] < target) lo = mid + 1; else hi = mid; }
    return lo;
}

__global__ __launch_bounds__(256) void k_pool2(const float* __restrict__ h, const int* __restrict__ batch,
                                               float* __restrict__ sums) {
    int g = blockIdx.x, chunk = blockIdx.y;
    __shared__ int sh[2];
    if (threadIdx.x < 2) sh[threadIdx.x] = lower_bound_g(batch, g + (int)threadIdx.x);
    __syncthreads();
    int lo = sh[0], hi = sh[1];
    float acc = 0.f;
    for (int r = lo + chunk; r < hi; r += 8)
        acc += h[(size_t)r * NO + threadIdx.x];
    atomicAdd(&sums[g * NO + threadIdx.x], acc);
}

__global__ __launch_bounds__(512) void k_final(const float* __restrict__ sums, const int* __restrict__ batch,
                                               const float* __restrict__ Wlin, const float* __restrict__ blin,
                                               float* __restrict__ out) {
    int g = blockIdx.x, t = threadIdx.x;
    __shared__ int sh[2];
    __shared__ float m[NO];
    if (t < 2) sh[t] = lower_bound_g(batch, g + t);
    __syncthreads();
    float inv = 1.f / (float)(sh[1] - sh[0]);
    if (t < NO) m[t] = sums[g * NO + t] * inv;
    __syncthreads();
    float acc = blin[t];
    for (int k = 0; k < NO; ++k) acc += m[k] * Wlin[(size_t)t * NO + k];
    out[(size_t)g * EMBD + t] = acc;
}

extern "C" void kernel_launch(void* const* d_in, const int* in_sizes, int n_in,
                              void* d_out, int out_size, void* d_ws, size_t ws_size,
                              hipStream_t stream) {
    const float* x     = (const float*)d_in[0];
    const int*   ei    = (const int*)d_in[1];
    const float* ef    = (const float*)d_in[2];
    const int*   batch = (const int*)d_in[3];
    const float* Wn0 = (const float*)d_in[4];
    const float* bn0 = (const float*)d_in[5];
    const float* We0 = (const float*)d_in[6];
    const float* be0 = (const float*)d_in[7];
    const float* Wm0 = (const float*)d_in[8];
    const float* bm0 = (const float*)d_in[9];
    const float* Wn  = (const float*)d_in[10];
    const float* bn  = (const float*)d_in[11];
    const float* We  = (const float*)d_in[12];
    const float* be  = (const float*)d_in[13];
    const float* Wm  = (const float*)d_in[14];
    const float* bm  = (const float*)d_in[15];
    const float* Wlin = (const float*)d_in[16];
    const float* blin = (const float*)d_in[17];
    float* out = (float*)d_out;

    // workspace carve (256B aligned slices)
    char* p = (char*)d_ws;
    auto carve = [&](size_t bytes) { char* q = p; p += (bytes + 255) & ~(size_t)255; return q; };
    float*  h    = (float*)carve((size_t)NNODES * NO * 4);            // 20.48 MB
    float*  HN   = (float*)carve((size_t)NNODES * NO * 4);            // 20.48 MB
    __half* UV   = (__half*)carve((size_t)NNODES * 512 * 2);          // 20.48 MB
    unsigned short* Whi = (unsigned short*)carve((size_t)NL * 768 * NO * 2);  // 11.0 MB
    unsigned short* Wlo = (unsigned short*)carve((size_t)NL * 768 * NO * 2);  // 11.0 MB
    float*  bcat = (float*)carve((size_t)NL * 768 * 4);
    float*  xpad = (float*)carve((size_t)NNODES * KPAD * 4);          // 5.12 MB
    int*    offs = (int*)carve((size_t)(NNODES + 1) * 4);
    int*    cur  = (int*)carve((size_t)NNODES * 4);
    int2*   em   = (int2*)carve((size_t)NEDGES * 8);                  // 5.12 MB
    float*  sums = (float*)carve((size_t)NGRAPHS * NO * 4);

    const int* src = ei;
    const int* dst = ei + NEDGES;

    // CSR build
    hipMemsetAsync(cur, 0, (size_t)NNODES * 4, stream);
    k_hist<<<NEDGES / 256, 256, 0, stream>>>(dst, cur);
    k_scan<<<1, 256, 0, stream>>>(cur, offs);
    k_copy<<<(NNODES + 255) / 256, 256, 0, stream>>>(offs, cur, NNODES);
    k_fill<<<NEDGES / 256, 256, 0, stream>>>(src, dst, ef, cur, em);

    // layer-0 padded input + composed per-layer weights (bf16 hi/lo)
    k_padx<<<(NNODES * KPAD + 255) / 256, 256, 0, stream>>>(x, xpad);
    k_prepA<<<(NL * NO * NO + 255) / 256, 256, 0, stream>>>(Wn0, bn0, Wn, bn, Whi, Wlo, bcat);
    k_prepB<<<NL * 32, 256, 0, stream>>>(Wn0, bn0, We0, be0, Wm0, bm0,
                                         Wn, bn, We, be, Wm, bm, Whi, Wlo, bcat);

    // 28 layers
    for (int l = 0; l < NL; ++l) {
        const float* Ain = (l == 0) ? xpad : h;
        int K = (l == 0) ? KPAD : NO;
        dim3 grid(768 / 128, (NNODES + 127) / 128);
        k_gemm<<<grid, 256, 0, stream>>>(Ain, Whi + (size_t)l * 768 * NO, Wlo + (size_t)l * 768 * NO,
                                         bcat + (size_t)l * 768, HN, UV, NNODES, K);
        k_edge<<<4 * NB, 256, 0, stream>>>(HN, UV, offs, em, h);
    }

    // mean-pool via sorted ranges, then tiny final GEMM
    hipMemsetAsync(sums, 0, (size_t)NGRAPHS * NO * 4, stream);
    dim3 pg(NGRAPHS, 8);
    k_pool2<<<pg, 256, 0, stream>>>(h, batch, sums);
    k_final<<<NGRAPHS, 512, 0, stream>>>(sums, batch, Wlin, blin, out);
}

// Round 12
// 3264.108 us; speedup vs baseline: 1.2182x; 1.0847x over previous
//
#include <hip/hip_runtime.h>
#include <hip/hip_fp16.h>

#define NNODES 20000
#define NEDGES 640000
#define NGRAPHS 16
#define NO     256
#define NNF    58
#define KPAD   64
#define EMBD   512
#define NL     28
#define NB     (NNODES / 4)   // edge-kernel node-blocks per pass

typedef __attribute__((ext_vector_type(8))) short bf16x8;
typedef __attribute__((ext_vector_type(4))) float f32x4;

__device__ __forceinline__ unsigned short f2bf(float f) {
    unsigned u = __float_as_uint(f);
    return (unsigned short)((u + 0x7fff + ((u >> 16) & 1)) >> 16);
}
__device__ __forceinline__ float bf2f(unsigned short h) {
    return __uint_as_float(((unsigned)h) << 16);
}

// ---------------- CSR build (once per launch) ----------------
__global__ __launch_bounds__(256) void k_hist(const int* __restrict__ dst, int* __restrict__ counts) {
    int e = blockIdx.x * 256 + threadIdx.x;
    if (e < NEDGES) atomicAdd(&counts[dst[e]], 1);
}

__global__ __launch_bounds__(256) void k_scan(const int* __restrict__ counts, int* __restrict__ offs) {
    __shared__ int part[256];
    int t = threadIdx.x;
    const int CH = (NNODES + 255) / 256;  // 79
    int base = t * CH;
    int s = 0;
    for (int i = 0; i < CH; ++i) { int idx = base + i; if (idx < NNODES) s += counts[idx]; }
    part[t] = s;
    __syncthreads();
    if (t == 0) { int acc = 0; for (int i = 0; i < 256; ++i) { int v = part[i]; part[i] = acc; acc += v; } }
    __syncthreads();
    int acc = part[t];
    for (int i = 0; i < CH; ++i) { int idx = base + i; if (idx < NNODES) { offs[idx] = acc; acc += counts[idx]; } }
    if (t == 255) offs[NNODES] = acc;
}

__global__ __launch_bounds__(256) void k_copy(const int* __restrict__ a, int* __restrict__ b, int n) {
    int i = blockIdx.x * 256 + threadIdx.x;
    if (i < n) b[i] = a[i];
}

// edge meta interleaved: em[pos] = (src, ef as packed half2) — ef pre-converted once
__global__ __launch_bounds__(256) void k_fill(const int* __restrict__ src, const int* __restrict__ dst,
                                              const float* __restrict__ ef, int* __restrict__ cursor,
                                              int2* __restrict__ em) {
    int e = blockIdx.x * 256 + threadIdx.x;
    if (e < NEDGES) {
        int d = dst[e];
        int pos = atomicAdd(&cursor[d], 1);
        float f = ef[e];
        __half2 hf = __floats2half2_rn(f, f);
        em[pos] = make_int2(src[e], *(int*)&hf);
    }
}

// ---------------- layer-0 input pad: [20000][58] -> [20000][64] fp32 ----------------
__global__ __launch_bounds__(256) void k_padx(const float* __restrict__ x, float* __restrict__ xpad) {
    int i = blockIdx.x * 256 + threadIdx.x;
    if (i < NNODES * KPAD) {
        int r = i >> 6, c = i & 63;
        xpad[i] = (c < NNF) ? x[r * NNF + c] : 0.f;
    }
}

// ---------------- weight precompute (bf16 hi/lo split) ----------------
// W rows: 0..255 = Wn; 256..511 = SCL*(Wm*diag(We))@Wn; 512..767 = SCL*(Wm*diag(be))@Wn
#define SCL 2.8853900817779268f

__global__ __launch_bounds__(256) void k_prepA(
    const float* __restrict__ Wn0, const float* __restrict__ bn0,
    const float* __restrict__ Wn,  const float* __restrict__ bn,
    unsigned short* __restrict__ Whi, unsigned short* __restrict__ Wlo,
    float* __restrict__ bcat) {
    int gid = blockIdx.x * 256 + threadIdx.x;
    if (gid >= NL * NO * NO) return;
    int l = gid / (NO * NO);
    int rem = gid % (NO * NO);
    int r = rem / NO, k = rem % NO;
    float w;
    if (l == 0) w = (k < NNF) ? Wn0[r * NNF + k] : 0.f;
    else        w = Wn[(size_t)(l - 1) * NO * NO + r * NO + k];
    unsigned short hi = f2bf(w);
    unsigned short lo = f2bf(w - bf2f(hi));
    size_t idx = ((size_t)l * 768 + r) * NO + k;
    Whi[idx] = hi; Wlo[idx] = lo;
    if (k == 0) bcat[l * 768 + r] = (l == 0) ? bn0[r] : bn[(l - 1) * NO + r];
}

// 8 rows/block (grid 28*64=1792 blocks: fixes grid-limited occupancy)
__global__ __launch_bounds__(256) void k_prepB(
    const float* __restrict__ Wn0, const float* __restrict__ bn0,
    const float* __restrict__ We0, const float* __restrict__ be0,
    const float* __restrict__ Wm0, const float* __restrict__ bm0,
    const float* __restrict__ Wn,  const float* __restrict__ bn,
    const float* __restrict__ We,  const float* __restrict__ be,
    const float* __restrict__ Wm,  const float* __restrict__ bm,
    unsigned short* __restrict__ Whi, unsigned short* __restrict__ Wlo,
    float* __restrict__ bcat) {
    int l = blockIdx.x >> 6;            // 28 layers
    int rr0 = (blockIdx.x & 63) * 8;    // 512 rows / 8
    int k = threadIdx.x;
    const float *wn, *bnv, *wev, *bev, *wm, *bmv;
    int K;
    if (l == 0) { wn = Wn0; bnv = bn0; wev = We0; bev = be0; wm = Wm0; bmv = bm0; K = NNF; }
    else {
        int j = l - 1;
        wn = Wn + (size_t)j * NO * NO; bnv = bn + j * NO;
        wev = We + j * NO;             bev = be + j * NO;
        wm = Wm + (size_t)j * NO * NO; bmv = bm + j * NO;
        K = NO;
    }
    __shared__ float coeff[8][NO + 1];
    for (int q = 0; q < 8; ++q) {
        int rr = rr0 + q;
        int i = rr & 255;
        const float* scale = (rr < 256) ? wev : bev;
        coeff[q][k] = wm[(size_t)i * NO + k] * scale[k];
    }
    __syncthreads();
    float acc[8] = {};
    if (k < K) {
        for (int j = 0; j < NO; ++j) {
            float wv = wn[(size_t)j * K + k];
            #pragma unroll
            for (int q = 0; q < 8; ++q) acc[q] += coeff[q][j] * wv;
        }
    }
    for (int q = 0; q < 8; ++q) {
        float w = (k < K) ? acc[q] * SCL : 0.f;
        unsigned short hi = f2bf(w);
        unsigned short lo = f2bf(w - bf2f(hi));
        size_t idx = ((size_t)l * 768 + 256 + rr0 + q) * NO + k;
        Whi[idx] = hi; Wlo[idx] = lo;
    }
    if (k < 8) {
        int rr = rr0 + k;
        int i = rr & 255;
        float b = 0.f;
        for (int j = 0; j < NO; ++j) b += coeff[k][j] * bnv[j];
        if (rr >= 256) b += bmv[i];
        bcat[l * 768 + 256 + rr] = b * SCL;
    }
}

// ---------------- MFMA layer GEMM (LDS-staged, on-the-fly A split) ----------------
#define LDP 40
__global__ __launch_bounds__(256) void k_gemm(const float* __restrict__ A,
                                              const unsigned short* __restrict__ Whi,
                                              const unsigned short* __restrict__ Wlo,
                                              const float* __restrict__ bias,
                                              float* __restrict__ HN, __half* __restrict__ UV,
                                              int M, int K) {
    __shared__ short sAhi[128 * LDP];
    __shared__ short sAlo[128 * LDP];
    __shared__ short sBhi[128 * LDP];
    __shared__ short sBlo[128 * LDP];
    int bn0 = blockIdx.x * 128;
    int bm0 = blockIdx.y * 128;
    int t = threadIdx.x;
    int wid = t >> 6, lane = t & 63;
    int wr = wid >> 1, wc = wid & 1;
    int lr = lane & 15, lg = lane >> 4;
    int kofs = lg * 8;
    f32x4 acc[4][4] = {};

    int srow = t >> 1, skh = (t & 1) * 16;

    for (int k0 = 0; k0 < K; k0 += 32) {
        {
            int gr = bm0 + srow;
            float f[16];
            if (gr < M) {
                #pragma unroll
                for (int q = 0; q < 4; ++q)
                    *(float4*)(f + 4 * q) = *(const float4*)(A + (size_t)gr * K + k0 + skh + 4 * q);
            } else {
                #pragma unroll
                for (int q = 0; q < 16; ++q) f[q] = 0.f;
            }
            int ph[8], pl[8];
            #pragma unroll
            for (int q = 0; q < 8; ++q) {
                unsigned short h0 = f2bf(f[2 * q]);
                unsigned short h1 = f2bf(f[2 * q + 1]);
                unsigned short l0 = f2bf(f[2 * q] - bf2f(h0));
                unsigned short l1 = f2bf(f[2 * q + 1] - bf2f(h1));
                ph[q] = (int)h0 | ((int)h1 << 16);
                pl[q] = (int)l0 | ((int)l1 << 16);
            }
            *(int4*)(void*)(sAhi + srow * LDP + skh)     = *(int4*)(void*)(ph);
            *(int4*)(void*)(sAhi + srow * LDP + skh + 8) = *(int4*)(void*)(ph + 4);
            *(int4*)(void*)(sAlo + srow * LDP + skh)     = *(int4*)(void*)(pl);
            *(int4*)(void*)(sAlo + srow * LDP + skh + 8) = *(int4*)(void*)(pl + 4);
        }
        {
            const unsigned short* gh = Whi + (size_t)(bn0 + srow) * NO + k0 + skh;
            const unsigned short* gl = Wlo + (size_t)(bn0 + srow) * NO + k0 + skh;
            *(int4*)(void*)(sBhi + srow * LDP + skh)     = *(const int4*)(void*)(gh);
            *(int4*)(void*)(sBhi + srow * LDP + skh + 8) = *(const int4*)(void*)(gh + 8);
            *(int4*)(void*)(sBlo + srow * LDP + skh)     = *(const int4*)(void*)(gl);
            *(int4*)(void*)(sBlo + srow * LDP + skh + 8) = *(const int4*)(void*)(gl + 8);
        }
        __syncthreads();
        bf16x8 ah[4], al[4], wh[4], wl[4];
        #pragma unroll
        for (int f = 0; f < 4; ++f) {
            ah[f] = *(bf16x8*)(void*)(sAhi + (wr * 64 + f * 16 + lr) * LDP + kofs);
            al[f] = *(bf16x8*)(void*)(sAlo + (wr * 64 + f * 16 + lr) * LDP + kofs);
            wh[f] = *(bf16x8*)(void*)(sBhi + (wc * 64 + f * 16 + lr) * LDP + kofs);
            wl[f] = *(bf16x8*)(void*)(sBlo + (wc * 64 + f * 16 + lr) * LDP + kofs);
        }
        #pragma unroll
        for (int fc = 0; fc < 4; ++fc)
            #pragma unroll
            for (int fr = 0; fr < 4; ++fr) {
                acc[fc][fr] = __builtin_amdgcn_mfma_f32_16x16x32_bf16(wh[fc], ah[fr], acc[fc][fr], 0, 0, 0);
                acc[fc][fr] = __builtin_amdgcn_mfma_f32_16x16x32_bf16(wh[fc], al[fr], acc[fc][fr], 0, 0, 0);
                acc[fc][fr] = __builtin_amdgcn_mfma_f32_16x16x32_bf16(wl[fc], ah[fr], acc[fc][fr], 0, 0, 0);
            }
        __syncthreads();
    }
    #pragma unroll
    for (int fc = 0; fc < 4; ++fc) {
        int n0 = bn0 + wc * 64 + fc * 16 + lg * 4;
        float4 bi = *(const float4*)(bias + n0);
        #pragma unroll
        for (int fr = 0; fr < 4; ++fr) {
            int gr = bm0 + wr * 64 + fr * 16 + lr;
            if (gr >= M) continue;
            f32x4 v = acc[fc][fr];
            float o0 = v[0] + bi.x, o1 = v[1] + bi.y, o2 = v[2] + bi.z, o3 = v[3] + bi.w;
            if (n0 < 256) {
                float4 o = {o0, o1, o2, o3};
                *(float4*)(HN + (size_t)gr * NO + n0) = o;
            } else {
                int i0 = (n0 < 512) ? n0 - 256 : n0 - 512;
                int base = 2 * i0 + ((n0 < 512) ? 0 : 4);
                union { __half2 h2[2]; uint2 u; } pk;
                pk.h2[0] = __floats2half2_rn(o0, o1);
                pk.h2[1] = __floats2half2_rn(o2, o3);
                *(uint2*)(UV + (size_t)gr * 512 + base) = pk.u;
            }
        }
    }
}

// ---------------- edge aggregation: channel-chunked + shfl meta + dual-edge inner loop ----------------
// pass c touches UV[:, 128c..128c+127]; wave = 4 edge-slots (es) x 16 channel-lanes (cl).
// Inner iteration processes 2 edges per lane (j0=i+es, j1=i+4+es): two INDEPENDENT gathers
// in flight back-to-back, halved per-edge loop overhead. Sum(tanh) = cnt - 2*Sum(rcp(exp2(z)+1)).
__global__ __launch_bounds__(256) void k_edge(const float* __restrict__ HN, const __half* __restrict__ UV,
                                              const int* __restrict__ offs,
                                              const int2* __restrict__ em,
                                              float* __restrict__ hout) {
    int blk = blockIdx.x;
    int pass = blk / NB;          // 0..3, linear dispatch keeps passes roughly sequential
    int nb   = blk - pass * NB;
    int wv = threadIdx.x >> 6;
    int lane = threadIdx.x & 63;
    int n = nb * 4 + wv;
    int es = lane >> 4, cl = lane & 15;
    int e0 = offs[n], e1 = offs[n + 1];
    float r0 = 0.f, r1 = 0.f, r2 = 0.f, r3 = 0.f;
    const __half* uvb = UV + pass * 128 + cl * 8;
    for (int eb = e0; eb < e1; eb += 64) {
        int cnt = e1 - eb; if (cnt > 64) cnt = 64;
        int2 mv = make_int2(0, 0);
        if (lane < cnt) mv = em[eb + lane];
        #pragma unroll 2
        for (int i = 0; i < cnt; i += 8) {
            int j0 = i + es, j1 = i + 4 + es;
            int s0 = __shfl(mv.x, j0);
            int f0 = __shfl(mv.y, j0);
            int s1 = __shfl(mv.x, j1);
            int f1 = __shfl(mv.y, j1);
            bool v0 = j0 < cnt, v1 = j1 < cnt;
            float4 raw0, raw1;
            if (v0) raw0 = *(const float4*)(uvb + (size_t)s0 * 512);
            if (v1) raw1 = *(const float4*)(uvb + (size_t)s1 * 512);
            if (v0) {
                const __half2* hp = (const __half2*)&raw0;
                __half2 f = *(__half2*)&f0;
                __half2 za = __hfma2(f, hp[0], hp[2]);
                __half2 zb = __hfma2(f, hp[1], hp[3]);
                float2 xa = __half22float2(za);
                float2 xb = __half22float2(zb);
                r0 += __builtin_amdgcn_rcpf(exp2f(xa.x) + 1.0f);
                r1 += __builtin_amdgcn_rcpf(exp2f(xa.y) + 1.0f);
                r2 += __builtin_amdgcn_rcpf(exp2f(xb.x) + 1.0f);
                r3 += __builtin_amdgcn_rcpf(exp2f(xb.y) + 1.0f);
            }
            if (v1) {
                const __half2* hp = (const __half2*)&raw1;
                __half2 f = *(__half2*)&f1;
                __half2 za = __hfma2(f, hp[0], hp[2]);
                __half2 zb = __hfma2(f, hp[1], hp[3]);
                float2 xa = __half22float2(za);
                float2 xb = __half22float2(zb);
                r0 += __builtin_amdgcn_rcpf(exp2f(xa.x) + 1.0f);
                r1 += __builtin_amdgcn_rcpf(exp2f(xa.y) + 1.0f);
                r2 += __builtin_amdgcn_rcpf(exp2f(xb.x) + 1.0f);
                r3 += __builtin_amdgcn_rcpf(exp2f(xb.y) + 1.0f);
            }
        }
    }
    r0 += __shfl_xor(r0, 16); r0 += __shfl_xor(r0, 32);
    r1 += __shfl_xor(r1, 16); r1 += __shfl_xor(r1, 32);
    r2 += __shfl_xor(r2, 16); r2 += __shfl_xor(r2, 32);
    r3 += __shfl_xor(r3, 16); r3 += __shfl_xor(r3, 32);
    if (es == 0) {
        float cnt = (float)(e1 - e0);
        int c0 = pass * 64 + cl * 4;
        float4 hn4 = *(const float4*)(HN + (size_t)n * NO + c0);
        float4 o = {hn4.x + cnt - 2.f * r0, hn4.y + cnt - 2.f * r1,
                    hn4.z + cnt - 2.f * r2, hn4.w + cnt - 2.f * r3};
        *(float4*)(hout + (size_t)n * NO + c0) = o;
    }
}

// ---------------- pooling via sorted-batch ranges ----------------
__device__ __forceinline__ int lower_bound_g(const int* __restrict__ batch, int target) {
    int lo = 0, hi = NNODES;
    while (lo < hi) { int mid = (lo + hi) >> 1; if (batch[mid] < target) lo = mid + 1; else hi = mid; }
    return lo;
}

__global__ __launch_bounds__(256) void k_pool2(const float* __restrict__ h, const int* __restrict__ batch,
                                               float* __restrict__ sums) {
    int g = blockIdx.x, chunk = blockIdx.y;
    __shared__ int sh[2];
    if (threadIdx.x < 2) sh[threadIdx.x] = lower_bound_g(batch, g + (int)threadIdx.x);
    __syncthreads();
    int lo = sh[0], hi = sh[1];
    float acc = 0.f;
    for (int r = lo + chunk; r < hi; r += 8)
        acc += h[(size_t)r * NO + threadIdx.x];
    atomicAdd(&sums[g * NO + threadIdx.x], acc);
}

__global__ __launch_bounds__(512) void k_final(const float* __restrict__ sums, const int* __restrict__ batch,
                                               const float* __restrict__ Wlin, const float* __restrict__ blin,
                                               float* __restrict__ out) {
    int g = blockIdx.x, t = threadIdx.x;
    __shared__ int sh[2];
    __shared__ float m[NO];
    if (t < 2) sh[t] = lower_bound_g(batch, g + t);
    __syncthreads();
    float inv = 1.f / (float)(sh[1] - sh[0]);
    if (t < NO) m[t] = sums[g * NO + t] * inv;
    __syncthreads();
    float acc = blin[t];
    for (int k = 0; k < NO; ++k) acc += m[k] * Wlin[(size_t)t * NO + k];
    out[(size_t)g * EMBD + t] = acc;
}

extern "C" void kernel_launch(void* const* d_in, const int* in_sizes, int n_in,
                              void* d_out, int out_size, void* d_ws, size_t ws_size,
                              hipStream_t stream) {
    const float* x     = (const float*)d_in[0];
    const int*   ei    = (const int*)d_in[1];
    const float* ef    = (const float*)d_in[2];
    const int*   batch = (const int*)d_in[3];
    const float* Wn0 = (const float*)d_in[4];
    const float* bn0 = (const float*)d_in[5];
    const float* We0 = (const float*)d_in[6];
    const float* be0 = (const float*)d_in[7];
    const float* Wm0 = (const float*)d_in[8];
    const float* bm0 = (const float*)d_in[9];
    const float* Wn  = (const float*)d_in[10];
    const float* bn  = (const float*)d_in[11];
    const float* We  = (const float*)d_in[12];
    const float* be  = (const float*)d_in[13];
    const float* Wm  = (const float*)d_in[14];
    const float* bm  = (const float*)d_in[15];
    const float* Wlin = (const float*)d_in[16];
    const float* blin = (const float*)d_in[17];
    float* out = (float*)d_out;

    // workspace carve (256B aligned slices)
    char* p = (char*)d_ws;
    auto carve = [&](size_t bytes) { char* q = p; p += (bytes + 255) & ~(size_t)255; return q; };
    float*  h    = (float*)carve((size_t)NNODES * NO * 4);            // 20.48 MB
    float*  HN   = (float*)carve((size_t)NNODES * NO * 4);            // 20.48 MB
    __half* UV   = (__half*)carve((size_t)NNODES * 512 * 2);          // 20.48 MB
    unsigned short* Whi = (unsigned short*)carve((size_t)NL * 768 * NO * 2);  // 11.0 MB
    unsigned short* Wlo = (unsigned short*)carve((size_t)NL * 768 * NO * 2);  // 11.0 MB
    float*  bcat = (float*)carve((size_t)NL * 768 * 4);
    float*  xpad = (float*)carve((size_t)NNODES * KPAD * 4);          // 5.12 MB
    int*    offs = (int*)carve((size_t)(NNODES + 1) * 4);
    int*    cur  = (int*)carve((size_t)NNODES * 4);
    int2*   em   = (int2*)carve((size_t)NEDGES * 8);                  // 5.12 MB
    float*  sums = (float*)carve((size_t)NGRAPHS * NO * 4);

    const int* src = ei;
    const int* dst = ei + NEDGES;

    // CSR build
    hipMemsetAsync(cur, 0, (size_t)NNODES * 4, stream);
    k_hist<<<NEDGES / 256, 256, 0, stream>>>(dst, cur);
    k_scan<<<1, 256, 0, stream>>>(cur, offs);
    k_copy<<<(NNODES + 255) / 256, 256, 0, stream>>>(offs, cur, NNODES);
    k_fill<<<NEDGES / 256, 256, 0, stream>>>(src, dst, ef, cur, em);

    // layer-0 padded input + composed per-layer weights (bf16 hi/lo)
    k_padx<<<(NNODES * KPAD + 255) / 256, 256, 0, stream>>>(x, xpad);
    k_prepA<<<(NL * NO * NO + 255) / 256, 256, 0, stream>>>(Wn0, bn0, Wn, bn, Whi, Wlo, bcat);
    k_prepB<<<NL * 64, 256, 0, stream>>>(Wn0, bn0, We0, be0, Wm0, bm0,
                                         Wn, bn, We, be, Wm, bm, Whi, Wlo, bcat);

    // 28 layers
    for (int l = 0; l < NL; ++l) {
        const float* Ain = (l == 0) ? xpad : h;
        int K = (l == 0) ? KPAD : NO;
        dim3 grid(768 / 128, (NNODES + 127) / 128);
        k_gemm<<<grid, 256, 0, stream>>>(Ain, Whi + (size_t)l * 768 * NO, Wlo + (size_t)l * 768 * NO,
                                         bcat + (size_t)l * 768, HN, UV, NNODES, K);
        k_edge<<<4 * NB, 256, 0, stream>>>(HN, UV, offs, em, h);
    }

    // mean-pool via sorted ranges, then tiny final GEMM
    hipMemsetAsync(sums, 0, (size_t)NGRAPHS * NO * 4, stream);
    dim3 pg(NGRAPHS, 8);
    k_pool2<<<pg, 256, 0, stream>>>(h, batch, sums);
    k_final<<<NGRAPHS, 512, 0, stream>>>(sums, batch, Wlin, blin, out);
}